// Round 9
// baseline (165.934 us; speedup 1.0000x reference)
//
#include <hip/hip_runtime.h>

// IGN 2->2 dense layer, N=4, M=256, D=32, S=32, fp32.
// out[n,i,j,s] = sum_d (C10[d,s]*in[n,i,j,d] + C11[d,s]*in[n,j,i,d])
//              + RW[n,i,s] + CW[n,j,s] + (i==j)*DW[n,i,s]

#define NN 4
#define MM 256
#define DD 32
#define SS 32

// ---- workspace layout (float offsets) ----
#define WS_COLSP  0        // [8][N*M*D] = 262144  cols partials (i-eighths)
#define WS_ROWS   262144   // [N*M*D] 32768
#define WS_DIAG   294912   // [N*M*D] 32768
#define WS_SD     327680   // [N*D] 128  (atomic; memset)
#define WS_TOT    327808   // [N*D] 128  (atomic; memset)
#define WS_RW     327936   // [N*M*S] 32768  (row-major: s_load in k_main)
#define WS_CWT4   360704   // [N][8][M] float4 = 32768 floats (s-vectorized CW)
#define WS_DW     393472   // [N*M*S] 32768
#define WS_CPACK  426240   // [15][D*S] 15360
// end: 441600 floats = 1766400 bytes

// k_reduce: blocks [0,256): cols partials; [256,1280): rows+diag+sd/tot;
// block 1280: coeff pack.
__global__ __launch_bounds__(256) void k_reduce(const float* __restrict__ in,
                                                const float* __restrict__ coeffs,
                                                float* __restrict__ ws) {
    int blk = blockIdx.x;
    int t = threadIdx.x;
    if (blk < 256) {
        // cols[n,j,d] partial over a 32-i slab.  Wave reads contiguous 1KB/instr.
        int n = blk >> 6, rem = blk & 63, jb = rem >> 3, ie = rem & 7;
        int i0 = ie * 32, j0 = jb * 32;
        int jl = t >> 3, d4 = t & 7;
        const float4* base = (const float4*)in
            + ((size_t)(n * MM + i0) * MM + j0 + jl) * 8 + d4;
        float4 a = {0.f, 0.f, 0.f, 0.f};
        #pragma unroll 8
        for (int i = 0; i < 32; ++i) {
            float4 v = base[(size_t)i * MM * 8];
            a.x += v.x; a.y += v.y; a.z += v.z; a.w += v.w;
        }
        ((float4*)(ws + WS_COLSP))[(size_t)ie * 8192 + (n * MM + j0 + jl) * 8 + d4] = a;
    } else if (blk < 256 + NN * MM) {
        // rows[nm,d] = sum_j in[nm,j,d]; diag; sd/tot atomics.
        int nm = blk - 256;            // n*M + i
        int n = nm >> 8;
        int ii = nm & 255;
        const float4* base = (const float4*)(in + (size_t)nm * MM * DD);
        // f4 idx = t + k*256 -> d4 = t&7 invariant over k.
        float4 a = {0.f, 0.f, 0.f, 0.f};
        #pragma unroll
        for (int k = 0; k < 8; ++k) {
            float4 v = base[t + k * 256];
            a.x += v.x; a.y += v.y; a.z += v.z; a.w += v.w;
        }
        __shared__ float4 red[256];
        red[t] = a;
        __syncthreads();
        if (t < 8) {
            float4 s = {0.f, 0.f, 0.f, 0.f};
            #pragma unroll 8
            for (int g = 0; g < 32; ++g) {
                float4 v = red[g * 8 + t];
                s.x += v.x; s.y += v.y; s.z += v.z; s.w += v.w;
            }
            ((float4*)(ws + WS_ROWS))[nm * 8 + t] = s;
            float4 dv = ((const float4*)in)[((size_t)nm * MM + ii) * 8 + t];
            ((float4*)(ws + WS_DIAG))[nm * 8 + t] = dv;
            atomicAdd(ws + WS_TOT + n * DD + t * 4 + 0, s.x);
            atomicAdd(ws + WS_TOT + n * DD + t * 4 + 1, s.y);
            atomicAdd(ws + WS_TOT + n * DD + t * 4 + 2, s.z);
            atomicAdd(ws + WS_TOT + n * DD + t * 4 + 3, s.w);
            atomicAdd(ws + WS_SD + n * DD + t * 4 + 0, dv.x);
            atomicAdd(ws + WS_SD + n * DD + t * 4 + 1, dv.y);
            atomicAdd(ws + WS_SD + n * DD + t * 4 + 2, dv.z);
            atomicAdd(ws + WS_SD + n * DD + t * 4 + 3, dv.w);
        }
    } else {
        // pack coeffs [D*S,15] -> [15][D*S]
        for (int idx = t; idx < 15 * DD * SS; idx += 256) {
            int plane = idx >> 10;
            int ds = idx & 1023;
            ws[WS_CPACK + plane * (DD * SS) + ds] = coeffs[ds * 15 + plane];
        }
    }
}

// k_aux: RW[n,m,s], CWT4[n][s/4][m], DW[n,m,s].  128 blocks; thread -> (n,m,s).
__global__ __launch_bounds__(256) void k_aux(const float* __restrict__ diag_bias,
                                             const float* __restrict__ all_bias,
                                             float* __restrict__ ws) {
    int idx = blockIdx.x * blockDim.x + threadIdx.x;   // over N*M*S
    int s = idx & 31;
    int nm = idx >> 5;                                  // n*M + m
    int n = nm >> 8;
    int m = nm & 255;
    const float inv_m = 1.0f / MM;
    const float inv_m2 = inv_m * inv_m;
    float u = 0.f, v = 0.f, dgacc = 0.f, w = 0.f;
    for (int d = 0; d < DD; ++d) {
        const float* cp = ws + WS_CPACK + d * SS + s;   // plane stride 1024
        float r = ws[WS_ROWS + nm * DD + d];
        float cl = 0.f;
        #pragma unroll
        for (int q = 0; q < 8; ++q) cl += ws[WS_COLSP + q * 32768 + nm * DD + d];
        float dv = ws[WS_DIAG + nm * DD + d];
        float sdv = ws[WS_SD + n * DD + d];
        float totv = ws[WS_TOT + n * DD + d];
        // i-dependent (all j): op6 cols_i/m, op7 rows_i/m, op12 diag_i
        u += cp[5 * 1024] * cl * inv_m + cp[6 * 1024] * r * inv_m + cp[11 * 1024] * dv;
        // j-dependent: op8 cols_j/m, op9 rows_j/m, op13 diag_j
        v += cp[7 * 1024] * cl * inv_m + cp[8 * 1024] * r * inv_m + cp[12 * 1024] * dv;
        // diagonal-only: op1..op5
        dgacc += cp[0] * dv + cp[1 * 1024] * sdv * inv_m + cp[2 * 1024] * r * inv_m
               + cp[3 * 1024] * cl * inv_m + cp[4 * 1024] * totv * inv_m2;
        // constant: op14 sd/m, op15 tot/m^2
        w += cp[13 * 1024] * sdv * inv_m + cp[14 * 1024] * totv * inv_m2;
    }
    ws[WS_RW + nm * SS + s] = u + w + all_bias[s];
    // s-vectorized transposed CW: float4 slot [(n*8 + s/4)*M + m], comp s%4
    ws[WS_CWT4 + (((n * 8 + (s >> 2)) * MM + m) << 2) + (s & 3)] = v;
    ws[WS_DW + nm * SS + s] = dgacc + diag_bias[s];
}

// k_main: block per (n,i) row; 256 threads = j.  All global I/O coalesced via
// LDS (rows padded to 36 floats).  B-loads issued before A-FMA phase so their
// latency hides under compute (load order A -> CWT/DW -> B keeps vmcnt counted).
__global__ __launch_bounds__(256) void k_main(const float* __restrict__ in,
                                              const float* __restrict__ ws,
                                              float* __restrict__ out) {
    __shared__ float tile[256 * 36];
    int nm = blockIdx.x;              // n*M + i
    int n = nm >> 8;
    int i = nm & 255;
    int t = threadIdx.x;              // j

    // (1) A-row loads (oldest in vmcnt queue)
    const float4* Arow = (const float4*)(in + (size_t)nm * MM * DD);
    float4 avv[8];
    #pragma unroll
    for (int k = 0; k < 8; ++k) avv[k] = Arow[t + k * 256];

    // (2) CWT4 + DW loads (retire before B)
    float4 cvv[8];
    const float4* cwt4 = (const float4*)(ws + WS_CWT4) + (size_t)n * 8 * MM + t;
    #pragma unroll
    for (int sq = 0; sq < 8; ++sq) cvv[sq] = cwt4[sq * MM];
    float4 dvv[8] = {};
    if (t == i) {
        const float4* dw = (const float4*)(ws + WS_DW + nm * SS);
        #pragma unroll
        for (int q = 0; q < 8; ++q) dvv[q] = dw[q];
    }

    // (3) B-column loads (newest; stay in flight through A-FMA phase)
    const float4* Bbase = (const float4*)in;
    float4 bvv[8];
    #pragma unroll
    for (int k = 0; k < 8; ++k) {
        int idx = t + k * 256;
        int p = idx >> 3, c = idx & 7;
        bvv[k] = Bbase[((size_t)(n * MM + p) * MM + i) * 8 + c];
    }
    __builtin_amdgcn_sched_barrier(0);

    // (4) stage A to LDS (waits only for A + CWT/DW, not B)
    #pragma unroll
    for (int k = 0; k < 8; ++k) {
        int idx = t + k * 256;
        int p = idx >> 3, c = idx & 7;
        *(float4*)(tile + p * 36 + c * 4) = avv[k];
    }
    __syncthreads();

    // (5) acc init: RW (wave-uniform -> s_load) + CWT4 + diag DW
    const float* rwp = ws + WS_RW + nm * SS;
    float acc[SS];
    #pragma unroll
    for (int sq = 0; sq < 8; ++sq) {
        acc[sq * 4 + 0] = rwp[sq * 4 + 0] + cvv[sq].x + dvv[sq].x;
        acc[sq * 4 + 1] = rwp[sq * 4 + 1] + cvv[sq].y + dvv[sq].y;
        acc[sq * 4 + 2] = rwp[sq * 4 + 2] + cvv[sq].z + dvv[sq].z;
        acc[sq * 4 + 3] = rwp[sq * 4 + 3] + cvv[sq].w + dvv[sq].w;
    }

    // (6) A-side FMAs (C10) from own LDS row
    const float* c10 = ws + WS_CPACK + 9 * (DD * SS);    // uniform -> s_load
    const float* c11 = ws + WS_CPACK + 10 * (DD * SS);
    const float* lrow = tile + t * 36;
    #pragma unroll
    for (int dq = 0; dq < 8; ++dq) {
        float4 a4 = *(const float4*)(lrow + dq * 4);
        const float* ca = c10 + dq * 4 * SS;
        #pragma unroll
        for (int r = 0; r < 4; ++r) {
            float a = (r == 0) ? a4.x : (r == 1) ? a4.y : (r == 2) ? a4.z : a4.w;
            #pragma unroll
            for (int s = 0; s < SS; ++s)
                acc[s] = fmaf(a, ca[r * SS + s], acc[s]);
        }
    }
    __syncthreads();

    // (7) stage B to LDS (B arrived during A-FMAs)
    #pragma unroll
    for (int k = 0; k < 8; ++k) {
        int idx = t + k * 256;
        int p = idx >> 3, c = idx & 7;
        *(float4*)(tile + p * 36 + c * 4) = bvv[k];
    }
    __syncthreads();

    // (8) B-side FMAs (C11)
    #pragma unroll
    for (int dq = 0; dq < 8; ++dq) {
        float4 b4 = *(const float4*)(lrow + dq * 4);
        const float* cb = c11 + dq * 4 * SS;
        #pragma unroll
        for (int r = 0; r < 4; ++r) {
            float bb = (r == 0) ? b4.x : (r == 1) ? b4.y : (r == 2) ? b4.z : b4.w;
            #pragma unroll
            for (int s = 0; s < SS; ++s)
                acc[s] = fmaf(bb, cb[r * SS + s], acc[s]);
        }
    }
    // own-row reads done; safe to overwrite own row
    #pragma unroll
    for (int q = 0; q < 8; ++q)
        *(float4*)(tile + t * 36 + q * 4) =
            make_float4(acc[q * 4 + 0], acc[q * 4 + 1], acc[q * 4 + 2], acc[q * 4 + 3]);
    __syncthreads();

    // (9) coalesced store of out[n,i,:,:] (32KB contiguous)
    float4* Orow = (float4*)(out + (size_t)nm * MM * SS);
    #pragma unroll
    for (int k = 0; k < 8; ++k) {
        int idx = t + k * 256;
        int p = idx >> 3, c = idx & 7;
        Orow[idx] = *(const float4*)(tile + p * 36 + c * 4);
    }
}

extern "C" void kernel_launch(void* const* d_in, const int* in_sizes, int n_in,
                              void* d_out, int out_size, void* d_ws, size_t ws_size,
                              hipStream_t stream) {
    const float* in = (const float*)d_in[0];
    // d_in[1] = mask (all-ones, unused by the reference math)
    const float* coeffs = (const float*)d_in[2];
    const float* diag_bias = (const float*)d_in[3];
    const float* all_bias = (const float*)d_in[4];
    float* out = (float*)d_out;
    float* ws = (float*)d_ws;

    // zero the atomic accumulators sd/tot (256 floats, contiguous)
    hipMemsetAsync((char*)d_ws + (size_t)WS_SD * 4, 0, 256 * sizeof(float), stream);
    k_reduce<<<256 + NN * MM + 1, 256, 0, stream>>>(in, coeffs, ws);
    k_aux<<<(NN * MM * SS) / 256, 256, 0, stream>>>(diag_bias, all_bias, ws);
    k_main<<<NN * MM, 256, 0, stream>>>(in, ws, out);
}